// Round 10
// baseline (379.259 us; speedup 1.0000x reference)
//
#include <hip/hip_runtime.h>
#include <hip/hip_fp16.h>
#include <math.h>

#define NB 64
#define NQ 300
#define NP 6
#define ND 256
#define NF 512
#define NCL 396
#define NT 10

// fp16 weight workspace layout (element offsets in halves)
#define IPW_OFF 0
#define INW_OFF 262144
#define OW_OFF  655360
#define L1W_OFF 786432
#define L2W_OFF 1048576
#define C1W_OFF 1310720
#define C2W_OFF 1441792
#define TOTW    1644544
#define CONV_BLOCKS 803   // TOTW / 2048
#define POOL_ROWS 65536   // 4 scales * NB * ND

typedef float f4 __attribute__((ext_vector_type(4)));

__device__ __forceinline__ float wred(float s) {
    #pragma unroll
    for (int o = 32; o; o >>= 1) s += __shfl_down(s, o, 64);
    return s;
}

// dot of 8 fp16 weights (packed in one 16B f4) with 8 f32 activations
__device__ __forceinline__ float dot8h(f4 wv, f4 xlo, f4 xhi) {
    const __half2* hp = reinterpret_cast<const __half2*>(&wv);
    float2 p0 = __half22float2(hp[0]);
    float2 p1 = __half22float2(hp[1]);
    float2 p2 = __half22float2(hp[2]);
    float2 p3 = __half22float2(hp[3]);
    return p0.x * xlo.x + p0.y * xlo.y + p1.x * xlo.z + p1.y * xlo.w
         + p2.x * xhi.x + p2.y * xhi.y + p3.x * xhi.z + p3.y * xhi.w;
}

// ---------------------------------------------------------------------------
// K1: blocks 0..63                  -> per-class masked mean pool + bias
//     blocks 64..64+65535           -> feat global-average-pool rows (4 scales!)
//     blocks 64+65536..+CONV_BLOCKS -> f32 -> fp16 weight conversion into ws
// ---------------------------------------------------------------------------
__global__ __launch_bounds__(256) void pool_cls_kernel(
    const float* __restrict__ pred, const float* __restrict__ hs,
    const float* __restrict__ f0, const float* __restrict__ f1,
    const float* __restrict__ f2, const float* __restrict__ f3,
    const float* __restrict__ ipw, const float* __restrict__ inw,
    const float* __restrict__ ow, const float* __restrict__ l1w,
    const float* __restrict__ l2w, const float* __restrict__ c1w,
    const float* __restrict__ c2w,
    float* __restrict__ pooled, float* __restrict__ tokG,
    float* __restrict__ biasW, __half* __restrict__ wH)
{
    const int bid = blockIdx.x;
    const int tid = threadIdx.x;
    __shared__ float shm[1824];

    if (bid < NB) {
        const int b = bid;
        float* maskL = shm;
        float* countsL = shm + 1800;
        for (int i = tid; i < NQ * NP; i += 256) {
            float x = pred[(size_t)b * NQ * NP + i];
            float sg = 1.f / (1.f + expf(-x));
            maskL[i] = (sg > 0.3f) ? 1.f : 0.f;
        }
        __syncthreads();
        if (tid < NP) {
            float c = 0.f;
            for (int q = 0; q < NQ; q++) c += maskL[q * NP + tid];
            countsL[tid] = c;
        }
        __syncthreads();
        float acc[NP] = {0.f, 0.f, 0.f, 0.f, 0.f, 0.f};
        const float* hsb = hs + (size_t)b * NQ * ND + tid;
        for (int q = 0; q < NQ; q++) {
            float h = hsb[(size_t)q * ND];
            #pragma unroll
            for (int p = 0; p < NP; p++) acc[p] += maskL[q * NP + p] * h;
        }
        bool anyv = false;
        #pragma unroll
        for (int p = 0; p < NP; p++) anyv = anyv || (countsL[p] > 0.f);
        #pragma unroll
        for (int p = 0; p < NP; p++) {
            float cm = acc[p] / fmaxf(countsL[p], 1.f);
            if (p == 0 && !anyv) cm = hs[(size_t)b * NQ * ND + tid];
            tokG[(size_t)b * 1536 + p * ND + tid] = cm;
        }
        if (tid < 16) {
            float bv = 0.f;
            if (tid < NP) {
                bool v = countsL[tid] > 0.f;
                if (tid == 0 && !anyv) v = true;
                bv = v ? 0.f : -1e30f;
            }
            biasW[b * 16 + tid] = bv;
        }
        return;
    }

    if (bid >= NB + POOL_ROWS) {
        // -------- weight conversion: 2048 elements per block --------
        const int cid = bid - (NB + POOL_ROWS);
        size_t base = (size_t)cid * 2048 + (size_t)tid * 8;
        const float* src; size_t off;
        if      (base < INW_OFF) { src = ipw; off = IPW_OFF; }
        else if (base < OW_OFF)  { src = inw; off = INW_OFF; }
        else if (base < L1W_OFF) { src = ow;  off = OW_OFF;  }
        else if (base < L2W_OFF) { src = l1w; off = L1W_OFF; }
        else if (base < C1W_OFF) { src = l2w; off = L2W_OFF; }
        else if (base < C2W_OFF) { src = c1w; off = C1W_OFF; }
        else                     { src = c2w; off = C2W_OFF; }
        const f4* s4 = reinterpret_cast<const f4*>(src + (base - off));
        f4 a = s4[0], b2 = s4[1];
        union { __half2 h[4]; f4 v; } u;
        u.h[0] = __floats2half2_rn(a.x, a.y);
        u.h[1] = __floats2half2_rn(a.z, a.w);
        u.h[2] = __floats2half2_rn(b2.x, b2.y);
        u.h[3] = __floats2half2_rn(b2.z, b2.w);
        *reinterpret_cast<f4*>(wH + base) = u.v;
        return;
    }

    // -------- feature pooling --------
    const int row = bid - NB;
    const int scale = row >> 14;
    const int rr = row & 16383;
    const int b = rr >> 8;
    const int d = rr & 255;
    const float* src;
    int n;
    switch (scale) {
        case 0: src = f0; n = 96 * 96; break;
        case 1: src = f1; n = 48 * 48; break;
        case 2: src = f2; n = 24 * 24; break;
        default: src = f3; n = 12 * 12; break;
    }
    const f4* p4 = reinterpret_cast<const f4*>(src + ((size_t)b * ND + d) * (size_t)n);
    int n4 = n >> 2;
    float s = 0.f;
    for (int i = tid; i < n4; i += 256) {
        f4 v = __builtin_nontemporal_load(&p4[i]);
        s += v.x + v.y + v.z + v.w;
    }
    s = wred(s);
    int wid = tid >> 6, lane = tid & 63;
    if (lane == 0) shm[wid] = s;
    __syncthreads();
    if (tid == 0) {
        float t = shm[0] + shm[1] + shm[2] + shm[3];
        pooled[((size_t)b * 4 + scale) * ND + d] = t / (float)n;
    }
}

// ---------------------------------------------------------------------------
// K2: fused per-batch transformer, fp16 weights, T=2 column pairing.
// 64 blocks x 1024 threads.
// ---------------------------------------------------------------------------
__global__ __launch_bounds__(1024) void xform_kernel(
    const float* __restrict__ pooled, const float* __restrict__ tokG,
    const float* __restrict__ biasW, const __half* __restrict__ wH,
    const float* __restrict__ ipb, const float* __restrict__ inb,
    const float* __restrict__ ob, const float* __restrict__ l1b,
    const float* __restrict__ l2b,
    const float* __restrict__ n1w, const float* __restrict__ n1b,
    const float* __restrict__ n2w, const float* __restrict__ n2b,
    const float* __restrict__ c1b, const float* __restrict__ c2b,
    float* __restrict__ out)
{
    const int b = blockIdx.x;
    const int tid = threadIdx.x;
    const int lane = tid & 63;
    const int wid = tid >> 6;

    __shared__ __align__(16) float xs[NT * ND];     // 2560 current x
    __shared__ __align__(16) float qs[4 * NT * ND]; // 10240 qkv / partials
    __shared__ __align__(16) float xr[NT * ND];     // 2560 attn-out / resid / ct
    __shared__ __align__(16) float h1[NT * NF];     // 5120 pld / ff hidden / hbuf
    __shared__ float sc[800];
    __shared__ float stats[32];
    __shared__ float biasK[16];

    const __half* ipwH = wH + IPW_OFF;
    const __half* inwH = wH + INW_OFF;
    const __half* owH  = wH + OW_OFF;
    const __half* l1wH = wH + L1W_OFF;
    const __half* l2wH = wH + L2W_OFF;
    const __half* c1wH = wH + C1W_OFF;
    const __half* c2wH = wH + C2W_OFF;

    // ---------------- stage ----------------
    for (int i = tid; i < 1536; i += 1024) xs[i] = tokG[(size_t)b * 1536 + i];
    h1[tid] = pooled[(size_t)b * 1024 + tid];        // pld
    if (tid < 16) biasK[tid] = biasW[b * 16 + tid];
    __syncthreads();

    const f4* xs4 = reinterpret_cast<const f4*>(xs);
    const f4* xr4 = reinterpret_cast<const f4*>(xr);
    const f4* h14 = reinterpret_cast<const f4*>(h1);

    // ---- img tokens: 1024 outputs, 1/thread, K=256 fp16 ----
    {
        const int i = tid >> 8, c = tid & 255;
        const f4* w4 = reinterpret_cast<const f4*>(ipwH + ((size_t)(i * ND + c)) * ND);
        float acc = 0.f;
        #pragma unroll 4
        for (int k8 = 0; k8 < 32; k8++)
            acc += dot8h(w4[k8], h14[i * 64 + 2 * k8], h14[i * 64 + 2 * k8 + 1]);
        __syncthreads();                              // pld reads done
        xs[(6 + i) * ND + c] = acc + ipb[i * ND + c];
    }
    __syncthreads();

    for (int l = 0; l < 2; l++) {
        // ---- (a) QKV: 384 owners x 2 cols, full K ----
        if (tid < 384) {
            const int c0 = tid, c1 = tid + 384;
            const f4* w0 = reinterpret_cast<const f4*>(inwH + ((size_t)l * 768 + c0) * ND);
            const f4* w1 = reinterpret_cast<const f4*>(inwH + ((size_t)l * 768 + c1) * ND);
            float a0[NT], a1[NT];
            #pragma unroll
            for (int r = 0; r < NT; r++) { a0[r] = 0.f; a1[r] = 0.f; }
            for (int k8 = 0; k8 < 32; k8++) {
                f4 wa = w0[k8], wb = w1[k8];
                #pragma unroll
                for (int r = 0; r < NT; r++) {
                    f4 xlo = xs4[r * 64 + 2 * k8], xhi = xs4[r * 64 + 2 * k8 + 1];
                    a0[r] += dot8h(wa, xlo, xhi);
                    a1[r] += dot8h(wb, xlo, xhi);
                }
            }
            float b0 = inb[l * 768 + c0], b1 = inb[l * 768 + c1];
            #pragma unroll
            for (int r = 0; r < NT; r++) {
                qs[r * 768 + c0] = a0[r] + b0;
                qs[r * 768 + c1] = a1[r] + b1;
            }
        }
        __syncthreads();

        // ---- (b) scores + bias ----
        if (tid < 800) {
            int h = tid / 100, rem = tid - 100 * h;
            int qr = rem / 10, kr = rem - 10 * qr;
            const float* qp = &qs[qr * 768 + h * 32];
            const float* kp = &qs[kr * 768 + ND + h * 32];
            float s = 0.f;
            #pragma unroll
            for (int dh = 0; dh < 32; dh++) s += qp[dh] * kp[dh];
            sc[tid] = s * 0.17677669529663687f + biasK[kr];
        }
        __syncthreads();

        // ---- (c) softmax ----
        if (tid < 80) {
            float* row = &sc[tid * 10];
            float m = row[0];
            #pragma unroll
            for (int k = 1; k < 10; k++) m = fmaxf(m, row[k]);
            float ss = 0.f;
            #pragma unroll
            for (int k = 0; k < 10; k++) { float e = expf(row[k] - m); row[k] = e; ss += e; }
            float inv = 1.f / ss;
            #pragma unroll
            for (int k = 0; k < 10; k++) row[k] *= inv;
        }
        __syncthreads();

        // ---- (d) attn @ V -> xr ----
        for (int idx = tid; idx < NT * ND; idx += 1024) {
            int r = idx >> 8, col = idx & 255, h = col >> 5;
            float s = 0.f;
            #pragma unroll
            for (int kr = 0; kr < 10; kr++)
                s += sc[h * 100 + r * 10 + kr] * qs[kr * 768 + 512 + col];
            xr[idx] = s;
        }
        __syncthreads();

        // ---- (e) out_proj: 128 owners x 2 cols x Ksplit4 (512 thr) ----
        {
            float a0[NT], a1[NT];
            const int kh = tid >> 7, c = tid & 127;   // kh 0..3 for tid<512
            if (tid < 512) {
                const f4* w0 = reinterpret_cast<const f4*>(owH + ((size_t)l * ND + c) * ND) + kh * 8;
                const f4* w1 = reinterpret_cast<const f4*>(owH + ((size_t)l * ND + c + 128) * ND) + kh * 8;
                #pragma unroll
                for (int r = 0; r < NT; r++) { a0[r] = 0.f; a1[r] = 0.f; }
                for (int k8 = 0; k8 < 8; k8++) {
                    f4 wa = w0[k8], wb = w1[k8];
                    #pragma unroll
                    for (int r = 0; r < NT; r++) {
                        f4 xlo = xr4[r * 64 + kh * 16 + 2 * k8], xhi = xr4[r * 64 + kh * 16 + 2 * k8 + 1];
                        a0[r] += dot8h(wa, xlo, xhi);
                        a1[r] += dot8h(wb, xlo, xhi);
                    }
                }
            }
            __syncthreads();             // xr reads done; qs(qkv) dead
            if (tid < 512) {
                #pragma unroll
                for (int r = 0; r < NT; r++) {
                    qs[kh * 2560 + r * ND + c] = a0[r];
                    qs[kh * 2560 + r * ND + c + 128] = a1[r];
                }
            }
        }
        __syncthreads();
        for (int idx = tid; idx < NT * ND; idx += 1024)
            xr[idx] = xs[idx] + qs[idx] + qs[2560 + idx] + qs[5120 + idx] + qs[7680 + idx]
                    + ob[l * ND + (idx & 255)];
        __syncthreads();

        // ---- (f) LN1: xr -> xs ----
        if (wid < NT) {
            int r = wid;
            float v0 = xr[r * ND + lane], v1 = xr[r * ND + 64 + lane];
            float v2 = xr[r * ND + 128 + lane], v3 = xr[r * ND + 192 + lane];
            float s = wred(v0 + v1 + v2 + v3);
            float q = wred(v0 * v0 + v1 * v1 + v2 * v2 + v3 * v3);
            if (lane == 0) {
                float m = s * (1.f / ND);
                stats[r] = m;
                stats[16 + r] = rsqrtf(fmaxf(q * (1.f / ND) - m * m, 0.f) + 1e-5f);
            }
        }
        __syncthreads();
        for (int idx = tid; idx < NT * ND; idx += 1024) {
            int r = idx >> 8, c = idx & 255;
            xs[idx] = (xr[idx] - stats[r]) * stats[16 + r] * n1w[l * ND + c] + n1b[l * ND + c];
        }
        __syncthreads();

        // ---- (g) FF1: 256 owners x 2 cols x Ksplit2 (512 thr) ----
        {
            float a0[NT], a1[NT];
            const int kh = tid >> 8, c = tid & 255;   // kh 0..1 for tid<512
            if (tid < 512) {
                const f4* w0 = reinterpret_cast<const f4*>(l1wH + ((size_t)l * NF + c) * ND) + kh * 16;
                const f4* w1 = reinterpret_cast<const f4*>(l1wH + ((size_t)l * NF + c + 256) * ND) + kh * 16;
                #pragma unroll
                for (int r = 0; r < NT; r++) { a0[r] = 0.f; a1[r] = 0.f; }
                for (int k8 = 0; k8 < 16; k8++) {
                    f4 wa = w0[k8], wb = w1[k8];
                    #pragma unroll
                    for (int r = 0; r < NT; r++) {
                        f4 xlo = xs4[r * 64 + kh * 32 + 2 * k8], xhi = xs4[r * 64 + kh * 32 + 2 * k8 + 1];
                        a0[r] += dot8h(wa, xlo, xhi);
                        a1[r] += dot8h(wb, xlo, xhi);
                    }
                }
                #pragma unroll
                for (int r = 0; r < NT; r++) {
                    qs[kh * 5120 + r * NF + c] = a0[r];
                    qs[kh * 5120 + r * NF + c + 256] = a1[r];
                }
            }
        }
        __syncthreads();
        for (int idx = tid; idx < NT * NF; idx += 1024)
            h1[idx] = fmaxf(qs[idx] + qs[5120 + idx] + l1b[l * NF + (idx & 511)], 0.f);
        __syncthreads();

        // ---- (h) FF2: 128 owners x 2 cols x Ksplit4 (512 thr) ----
        {
            float a0[NT], a1[NT];
            const int kh = tid >> 7, c = tid & 127;
            if (tid < 512) {
                const f4* w0 = reinterpret_cast<const f4*>(l2wH + ((size_t)l * ND + c) * NF) + kh * 16;
                const f4* w1 = reinterpret_cast<const f4*>(l2wH + ((size_t)l * ND + c + 128) * NF) + kh * 16;
                #pragma unroll
                for (int r = 0; r < NT; r++) { a0[r] = 0.f; a1[r] = 0.f; }
                for (int k8 = 0; k8 < 16; k8++) {
                    f4 wa = w0[k8], wb = w1[k8];
                    #pragma unroll
                    for (int r = 0; r < NT; r++) {
                        f4 xlo = h14[r * 128 + kh * 32 + 2 * k8], xhi = h14[r * 128 + kh * 32 + 2 * k8 + 1];
                        a0[r] += dot8h(wa, xlo, xhi);
                        a1[r] += dot8h(wb, xlo, xhi);
                    }
                }
            }
            __syncthreads();             // h1 reads + old qs reads done
            if (tid < 512) {
                #pragma unroll
                for (int r = 0; r < NT; r++) {
                    qs[kh * 2560 + r * ND + c] = a0[r];
                    qs[kh * 2560 + r * ND + c + 128] = a1[r];
                }
            }
        }
        __syncthreads();
        for (int idx = tid; idx < NT * ND; idx += 1024)
            xr[idx] = xs[idx] + qs[idx] + qs[2560 + idx] + qs[5120 + idx] + qs[7680 + idx]
                    + l2b[l * ND + (idx & 255)];
        __syncthreads();

        // ---- (i) LN2: xr -> xs ----
        if (wid < NT) {
            int r = wid;
            float v0 = xr[r * ND + lane], v1 = xr[r * ND + 64 + lane];
            float v2 = xr[r * ND + 128 + lane], v3 = xr[r * ND + 192 + lane];
            float s = wred(v0 + v1 + v2 + v3);
            float q = wred(v0 * v0 + v1 * v1 + v2 * v2 + v3 * v3);
            if (lane == 0) {
                float m = s * (1.f / ND);
                stats[r] = m;
                stats[16 + r] = rsqrtf(fmaxf(q * (1.f / ND) - m * m, 0.f) + 1e-5f);
            }
        }
        __syncthreads();
        for (int idx = tid; idx < NT * ND; idx += 1024) {
            int r = idx >> 8, c = idx & 255;
            xs[idx] = (xr[idx] - stats[r]) * stats[16 + r] * n2w[l * ND + c] + n2b[l * ND + c];
        }
        __syncthreads();
    }

    // ---------------- epilogue ----------------
    // masked mean pool -> xr[0..256)   (ct)
    if (tid < ND) {
        float len = 0.f, s = 0.f;
        #pragma unroll
        for (int r = 0; r < NT; r++) {
            float v = (biasK[r] == 0.f) ? 1.f : 0.f;
            len += v;
            s += v * xs[r * ND + tid];
        }
        xr[tid] = s / fmaxf(len, 1.f);
    }
    __syncthreads();

    // cls1: 256 owners x 2 cols x Ksplit2 (512 thr) -> h1[0..512)
    {
        const int kh = tid >> 8, c = tid & 255;
        if (tid < 512) {
            const f4* w0 = reinterpret_cast<const f4*>(c1wH + (size_t)c * ND) + kh * 16;
            const f4* w1 = reinterpret_cast<const f4*>(c1wH + (size_t)(c + 256) * ND) + kh * 16;
            float a0 = 0.f, a1 = 0.f;
            #pragma unroll 4
            for (int k8 = 0; k8 < 16; k8++) {
                f4 xlo = xr4[kh * 32 + 2 * k8], xhi = xr4[kh * 32 + 2 * k8 + 1];
                a0 += dot8h(w0[k8], xlo, xhi);
                a1 += dot8h(w1[k8], xlo, xhi);
            }
            qs[kh * 512 + c] = a0;
            qs[kh * 512 + c + 256] = a1;
        }
    }
    __syncthreads();
    if (tid < 512) h1[tid] = fmaxf(qs[tid] + qs[512 + tid] + c1b[tid], 0.f);
    __syncthreads();

    // cls2: 396 outputs x Ksplit2
    {
        const int kh = tid >> 9, o = tid & 511;
        if (o < NCL) {
            const f4* w4 = reinterpret_cast<const f4*>(c2wH + (size_t)o * NF) + kh * 32;
            float acc = 0.f;
            #pragma unroll 4
            for (int k8 = 0; k8 < 32; k8++)
                acc += dot8h(w4[k8], h14[kh * 64 + 2 * k8], h14[kh * 64 + 2 * k8 + 1]);
            qs[kh * 512 + o] = acc;
        }
    }
    __syncthreads();
    if (tid < NCL) out[(size_t)b * NCL + tid] = qs[tid] + qs[512 + tid] + c2b[tid];
}

// ---------------------------------------------------------------------------
extern "C" void kernel_launch(void* const* d_in, const int* in_sizes, int n_in,
                              void* d_out, int out_size, void* d_ws, size_t ws_size,
                              hipStream_t stream)
{
    const float* pred = (const float*)d_in[0];
    const float* hs   = (const float*)d_in[1];
    const float* f0   = (const float*)d_in[2];
    const float* f1   = (const float*)d_in[3];
    const float* f2   = (const float*)d_in[4];
    const float* f3   = (const float*)d_in[5];
    const float* ipw  = (const float*)d_in[6];
    const float* ipb  = (const float*)d_in[7];
    const float* inw  = (const float*)d_in[8];
    const float* inb  = (const float*)d_in[9];
    const float* ow   = (const float*)d_in[10];
    const float* ob   = (const float*)d_in[11];
    const float* l1w  = (const float*)d_in[12];
    const float* l1b  = (const float*)d_in[13];
    const float* l2w  = (const float*)d_in[14];
    const float* l2b  = (const float*)d_in[15];
    const float* ln1w = (const float*)d_in[16];
    const float* ln1b = (const float*)d_in[17];
    const float* ln2w = (const float*)d_in[18];
    const float* ln2b = (const float*)d_in[19];
    const float* c1w  = (const float*)d_in[20];
    const float* c1b  = (const float*)d_in[21];
    const float* c2w  = (const float*)d_in[22];
    const float* c2b  = (const float*)d_in[23];

    float* ws = (float*)d_ws;
    float* pooled = ws;                    // 65536 f
    float* tokG   = pooled + NB * 4 * ND;  // 98304 f
    float* biasW  = tokG + NB * 1536;      // 1024 f
    __half* wH    = (__half*)(biasW + 1024);  // 1644544 halves

    pool_cls_kernel<<<NB + POOL_ROWS + CONV_BLOCKS, 256, 0, stream>>>(
        pred, hs, f0, f1, f2, f3, ipw, inw, ow, l1w, l2w, c1w, c2w,
        pooled, tokG, biasW, wH);
    xform_kernel<<<NB, 1024, 0, stream>>>(
        pooled, tokG, biasW, wH, ipb, inb, ob, l1b, l2b,
        ln1w, ln1b, ln2w, ln2b, c1b, c2b, (float*)d_out);
}